// Round 2
// baseline (625.175 us; speedup 1.0000x reference)
//
#include <hip/hip_runtime.h>
#include <hip/hip_bf16.h>

#define B_ 2
#define T_ 2048
#define C_ 1280
#define H_ 10
#define D_ 128
#define BT_ (B_*T_)

typedef __hip_bfloat16 bf16;
typedef __attribute__((ext_vector_type(8))) short short8;
typedef __attribute__((ext_vector_type(4))) float f32x4;

__device__ __forceinline__ float bf2f(bf16 v){ return __bfloat162float(v); }
__device__ __forceinline__ bf16  f2bf(float v){ return __float2bfloat16(v); }
__device__ __forceinline__ void stv(bf16* p, float v){ *p = f2bf(v); }
__device__ __forceinline__ void stv(float* p, float v){ *p = v; }

struct alignas(8) bf4 { bf16 a,b,c,d; };

// ---- fp32 -> bf16 bulk convert (n multiple of 4) ----
__global__ __launch_bounds__(256)
void cvt(const float* __restrict__ s, bf16* __restrict__ d)
{
    const int i = (blockIdx.x*256 + threadIdx.x)*4;
    const float4 v = *(const float4*)(s + i);
    bf4 o = { f2bf(v.x), f2bf(v.y), f2bf(v.z), f2bf(v.w) };
    *(bf4*)(d + i) = o;
}

// 4 same-size weight matrices, blockIdx.y selects
__global__ __launch_bounds__(256)
void cvtW(const float* __restrict__ s0, const float* __restrict__ s1,
          const float* __restrict__ s2, const float* __restrict__ s3,
          bf16* __restrict__ d)   // d: 4 matrices back to back
{
    const int w = blockIdx.y;
    const float* s = (w==0)?s0:(w==1)?s1:(w==2)?s2:s3;
    const int i = (blockIdx.x*256 + threadIdx.x)*4;
    const float4 v = *(const float4*)(s + i);
    bf4 o = { f2bf(v.x), f2bf(v.y), f2bf(v.z), f2bf(v.w) };
    *(bf4*)(d + (size_t)w*C_*C_ + i) = o;
}

// ---- GEMM: O[4096,1280] = A[4096,1280] @ W[1280,1280]^T (NT, bf16 in, fp32 accum) ----
// block = 256 thr = 4 waves; block tile 128x128; wave tile 64x64 (4x4 MFMA 16x16x32).
template <typename OT>
__global__ __launch_bounds__(256)
void gemm_nt(const bf16* __restrict__ A, const bf16* __restrict__ Wb,
             OT* __restrict__ O0, OT* __restrict__ O1, OT* __restrict__ O2)
{
    const int z = blockIdx.z;
    const bf16* Wm = Wb + (size_t)z*C_*C_;
    OT*         Om = (z==0) ? O0 : (z==1) ? O1 : O2;
    const int wave = threadIdx.x >> 6;
    const int lane = threadIdx.x & 63;
    const int l15 = lane & 15, quad = lane >> 4;
    const int row0 = blockIdx.x*128 + (wave>>1)*64;
    const int col0 = blockIdx.y*128 + (wave&1)*64;
    const bf16* Ap = A  + (size_t)(row0 + l15)*C_ + quad*8;
    const bf16* Wp = Wm + (size_t)(col0 + l15)*C_ + quad*8;
    const f32x4 fzero = {0.f,0.f,0.f,0.f};
    f32x4 acc[4][4];
    #pragma unroll
    for (int i=0;i<4;i++)
        #pragma unroll
        for (int j=0;j<4;j++) acc[i][j] = fzero;
    for (int k = 0; k < C_; k += 32) {
        short8 af[4], bfv[4];
        #pragma unroll
        for (int mt=0; mt<4; ++mt) af[mt]  = *(const short8*)(Ap + (size_t)mt*16*C_ + k);
        #pragma unroll
        for (int nt=0; nt<4; ++nt) bfv[nt] = *(const short8*)(Wp + (size_t)nt*16*C_ + k);
        #pragma unroll
        for (int mt=0; mt<4; ++mt)
            #pragma unroll
            for (int nt=0; nt<4; ++nt)
                acc[mt][nt] = __builtin_amdgcn_mfma_f32_16x16x32_bf16(af[mt], bfv[nt], acc[mt][nt], 0,0,0);
    }
    #pragma unroll
    for (int mt=0; mt<4; ++mt)
        #pragma unroll
        for (int nt=0; nt<4; ++nt)
            #pragma unroll
            for (int r=0; r<4; ++r)
                stv(&Om[(size_t)(row0 + mt*16 + quad*4 + r)*C_ + col0 + nt*16 + l15], acc[mt][nt][r]);
}

// ---- RoPE + RMS-norm, in place on q or k (blockIdx.y selects). 4 rows/block, 1 wave/row. ----
__global__ __launch_bounds__(256)
void rope_rms(bf16* __restrict__ q, bf16* __restrict__ k,
              const float* __restrict__ cosp, const float* __restrict__ sinp)
{
    const int wave = threadIdx.x >> 6, lane = threadIdx.x & 63;
    const long rb = (long)blockIdx.x*4 + wave;           // [0, BT_*H_)
    const int h = (int)(rb % H_);
    const long bt = rb / H_;
    const int t = (int)(bt % T_);
    bf16* buf = blockIdx.y ? k : q;
    const size_t base = (size_t)bt*C_ + (size_t)h*D_;
    float x1 = bf2f(buf[base + lane]);
    float x2 = bf2f(buf[base + 64 + lane]);
    float c  = cosp[(size_t)t*64 + lane];
    float s  = sinp[(size_t)t*64 + lane];
    float y1 =  x1*c + x2*s;
    float y2 = -x1*s + x2*c;
    float ss = y1*y1 + y2*y2;
    #pragma unroll
    for (int off=1; off<64; off<<=1) ss += __shfl_xor(ss, off);
    float sc = rsqrtf(ss*(1.0f/128.0f) + 1e-5f);
    buf[base + lane]      = f2bf(y1*sc);
    buf[base + 64 + lane] = f2bf(y2*sc);
}

// ---- V transpose: Vt[bh][d][t] = V[(b*T+t)*C + h*D + d] ----
__global__ __launch_bounds__(256)
void vtrans(const bf16* __restrict__ V, bf16* __restrict__ Vt)
{
    __shared__ float st[64][65];
    const int tid = threadIdx.x;
    const int bh = blockIdx.z;
    const int b = bh / H_, h = bh % H_;
    const int t0 = blockIdx.x*64, d0 = blockIdx.y*64;
    #pragma unroll
    for (int i=0;i<16;i++){
        int e = tid + i*256;
        int r = e >> 6, dd = e & 63;
        st[r][dd] = bf2f(V[(size_t)(b*T_ + t0 + r)*C_ + h*D_ + d0 + dd]);
    }
    __syncthreads();
    #pragma unroll
    for (int i=0;i<16;i++){
        int e = tid + i*256;
        int dd = e >> 6, r = e & 63;
        Vt[((size_t)bh*D_ + d0 + dd)*T_ + t0 + r] = f2bf(st[r][dd]);
    }
}

// ---- Flash attention, causal. 1 wave/block, 16 q-rows per wave, 32-key chunks. ----
__global__ __launch_bounds__(64)
void attn(const bf16* __restrict__ Q, const bf16* __restrict__ K,
          const bf16* __restrict__ Vt, bf16* __restrict__ Y)
{
    __shared__ __align__(16) bf16 pt[16][40];   // P tile, row stride 80B (16B-aligned b128 reads)
    const int lane = threadIdx.x;
    const int l15 = lane & 15, quad = lane >> 4;
    const int bh = blockIdx.y, b = bh / H_, h = bh % H_;
    const int t0 = T_ - 16 - 16*blockIdx.x;     // reversed: big-work blocks first
    const size_t base = (size_t)b*T_*C_ + (size_t)h*D_;

    short8 qa[4];
    {
        const bf16* qp = Q + base + (size_t)(t0 + l15)*C_ + quad*8;
        #pragma unroll
        for (int kb=0; kb<4; ++kb) qa[kb] = *(const short8*)(qp + kb*32);
    }
    const f32x4 fzero = {0.f,0.f,0.f,0.f};
    f32x4 o[8];
    #pragma unroll
    for (int dt=0; dt<8; ++dt) o[dt] = fzero;
    float m[4] = {-1e30f,-1e30f,-1e30f,-1e30f};
    float l[4] = {0.f,0.f,0.f,0.f};
    const float scale = 0.08838834764831845f;   // 1/sqrt(128)
    const int nch = (t0 + 15)/32 + 1;

    for (int ch=0; ch<nch; ++ch) {
        const int k0 = ch*32;
        f32x4 sA = fzero, sB = fzero;
        const bf16* kp = K + base + (size_t)(k0 + l15)*C_ + quad*8;
        #pragma unroll
        for (int kb=0; kb<4; ++kb) {
            short8 bA = *(const short8*)(kp + kb*32);
            sA = __builtin_amdgcn_mfma_f32_16x16x32_bf16(qa[kb], bA, sA, 0,0,0);
        }
        const bf16* kp2 = kp + 16*C_;
        #pragma unroll
        for (int kb=0; kb<4; ++kb) {
            short8 bB = *(const short8*)(kp2 + kb*32);
            sB = __builtin_amdgcn_mfma_f32_16x16x32_bf16(qa[kb], bB, sB, 0,0,0);
        }
        float alpha[4];
        #pragma unroll
        for (int r=0; r<4; ++r) {
            const int rt = t0 + quad*4 + r;
            float a  = sA[r]*scale;
            float bb = sB[r]*scale;
            if (k0 + l15      > rt) a  = -1e30f;
            if (k0 + 16 + l15 > rt) bb = -1e30f;
            float mx = fmaxf(a, bb);
            #pragma unroll
            for (int off=1; off<16; off<<=1) mx = fmaxf(mx, __shfl_xor(mx, off));
            const float mn = fmaxf(m[r], mx);
            alpha[r] = __expf(m[r] - mn);
            const float pA = __expf(a - mn), pB = __expf(bb - mn);
            float rs = pA + pB;
            #pragma unroll
            for (int off=1; off<16; off<<=1) rs += __shfl_xor(rs, off);
            l[r] = l[r]*alpha[r] + rs;
            m[r] = mn;
            pt[quad*4+r][l15]      = f2bf(pA);
            pt[quad*4+r][16 + l15] = f2bf(pB);
        }
        #pragma unroll
        for (int dt=0; dt<8; ++dt)
            #pragma unroll
            for (int r=0; r<4; ++r) o[dt][r] *= alpha[r];
        asm volatile("s_waitcnt lgkmcnt(0)" ::: "memory");   // P tile visible (intra-wave)
        const short8 pa = *(const short8*)(&pt[l15][quad*8]);
        const bf16* vp = Vt + ((size_t)bh*D_ + l15)*T_ + k0 + quad*8;
        #pragma unroll
        for (int dt=0; dt<8; ++dt) {
            short8 bV = *(const short8*)(vp + (size_t)dt*16*T_);
            o[dt] = __builtin_amdgcn_mfma_f32_16x16x32_bf16(pa, bV, o[dt], 0,0,0);
        }
    }
    #pragma unroll
    for (int r=0; r<4; ++r) l[r] = 1.0f / l[r];
    #pragma unroll
    for (int dt=0; dt<8; ++dt)
        #pragma unroll
        for (int r=0; r<4; ++r)
            Y[base + (size_t)(t0 + quad*4 + r)*C_ + dt*16 + l15] = f2bf(o[dt][r]*l[r]);
}

extern "C" void kernel_launch(void* const* d_in, const int* in_sizes, int n_in,
                              void* d_out, int out_size, void* d_ws, size_t ws_size,
                              hipStream_t stream)
{
    const float* x    = (const float*)d_in[0];
    const float* cosp = (const float*)d_in[1];
    const float* sinp = (const float*)d_in[2];
    const float* Wq   = (const float*)d_in[3];
    const float* Wk   = (const float*)d_in[4];
    const float* Wv   = (const float*)d_in[5];
    const float* Wp   = (const float*)d_in[6];
    float* out = (float*)d_out;

    const size_t NE = (size_t)BT_ * C_;      // 5,242,880
    const size_t NW = (size_t)C_ * C_;       // 1,638,400
    bf16* xb = (bf16*)d_ws;                  // [BT,C]
    bf16* wb = xb + NE;                      // 4 weights back-to-back (q,k,v,proj)
    bf16* q  = wb + 4*NW;
    bf16* k  = q + NE;
    bf16* v  = k + NE;
    bf16* y  = v + NE;
    bf16* vT = y + NE;                       // [B*H][D][T]

    // fp32 -> bf16
    cvt<<<dim3(NE/1024), 256, 0, stream>>>(x, xb);
    cvtW<<<dim3(NW/1024, 4), 256, 0, stream>>>(Wq, Wk, Wv, Wp, wb);
    // q,k,v = x @ {Wq,Wk,Wv}^T
    gemm_nt<bf16><<<dim3(BT_/128, C_/128, 3), 256, 0, stream>>>(xb, wb, q, k, v);
    // RoPE + RMS on q and k (in place)
    rope_rms<<<dim3(BT_*H_/4, 2), 256, 0, stream>>>(q, k, cosp, sinp);
    // V transpose for PV MFMA B-fragments
    vtrans<<<dim3(T_/64, D_/64, B_*H_), 256, 0, stream>>>(v, vT);
    // causal flash attention -> y
    attn<<<dim3(T_/16, B_*H_), 64, 0, stream>>>(q, k, vT, y);
    // out = y @ Wproj^T (fp32 output)
    gemm_nt<float><<<dim3(BT_/128, C_/128, 1), 256, 0, stream>>>(y, wb + 3*NW, out, out, out);
}

// Round 3
// 568.409 us; speedup vs baseline: 1.0999x; 1.0999x over previous
//
#include <hip/hip_runtime.h>
#include <hip/hip_bf16.h>

#define B_ 2
#define T_ 2048
#define C_ 1280
#define H_ 10
#define D_ 128
#define BT_ (B_*T_)

typedef __hip_bfloat16 bf16;
typedef __attribute__((ext_vector_type(8))) short short8;
typedef __attribute__((ext_vector_type(4))) float f32x4;

__device__ __forceinline__ float bf2f(bf16 v){ return __bfloat162float(v); }
__device__ __forceinline__ bf16  f2bf(float v){ return __float2bfloat16(v); }
__device__ __forceinline__ void stv(bf16* p, float v){ *p = f2bf(v); }
__device__ __forceinline__ void stv(float* p, float v){ *p = v; }

struct alignas(8) bf4 { bf16 a,b,c,d; };

// async global->LDS, 16B per lane. lds ptr must be wave-uniform (HW adds lane*16).
__device__ __forceinline__ void gl2lds(const bf16* g, bf16* l) {
    __builtin_amdgcn_global_load_lds(
        (const __attribute__((address_space(1))) void*)g,
        (__attribute__((address_space(3))) void*)l,
        16, 0, 0);
}

// ---- fp32 -> bf16 bulk convert ----
__global__ __launch_bounds__(256)
void cvt(const float* __restrict__ s, bf16* __restrict__ d)
{
    const int i = (blockIdx.x*256 + threadIdx.x)*4;
    const float4 v = *(const float4*)(s + i);
    bf4 o = { f2bf(v.x), f2bf(v.y), f2bf(v.z), f2bf(v.w) };
    *(bf4*)(d + i) = o;
}

__global__ __launch_bounds__(256)
void cvtW(const float* __restrict__ s0, const float* __restrict__ s1,
          const float* __restrict__ s2, const float* __restrict__ s3,
          bf16* __restrict__ d)
{
    const int w = blockIdx.y;
    const float* s = (w==0)?s0:(w==1)?s1:(w==2)?s2:s3;
    const int i = (blockIdx.x*256 + threadIdx.x)*4;
    const float4 v = *(const float4*)(s + i);
    bf4 o = { f2bf(v.x), f2bf(v.y), f2bf(v.z), f2bf(v.w) };
    *(bf4*)(d + (size_t)w*C_*C_ + i) = o;
}

// ---- GEMM (m97 structure): O = A[4096,1280] @ W[1280,1280]^T, bf16 in, fp32 acc ----
// 256 thr / 4 waves; block tile 128x128, BK=32; global_load_lds width-16 staging.
template <typename OT>
__global__ __launch_bounds__(256)
void gemm_nt(const bf16* __restrict__ A, const bf16* __restrict__ Wb,
             OT* __restrict__ O0, OT* __restrict__ O1, OT* __restrict__ O2)
{
    __shared__ __align__(16) bf16 As[128*32];   // [m][k] row-major, 8 KB
    __shared__ __align__(16) bf16 Bs[128*32];   // [n][k] row-major, 8 KB
    const int z = blockIdx.z;
    const bf16* Wm = Wb + (size_t)z*C_*C_;
    OT*         Om = (z==0) ? O0 : (z==1) ? O1 : O2;
    const int wave = threadIdx.x >> 6;
    const int lane = threadIdx.x & 63;
    const int l15 = lane & 15, quad = lane >> 4;
    const int row0 = blockIdx.x*128;
    const int col0 = blockIdx.y*128;
    const int wm = (wave>>1)*64, wn = (wave&1)*64;
    const int srow = lane >> 2;          // 0..15
    const int scol = (lane & 3)*8;       // 0,8,16,24

    const f32x4 fzero = {0.f,0.f,0.f,0.f};
    f32x4 acc[4][4];
    #pragma unroll
    for (int i=0;i<4;i++)
        #pragma unroll
        for (int j=0;j<4;j++) acc[i][j] = fzero;

    const bf16* Ag = A  + (size_t)(row0 + wave*32 + srow)*C_ + scol;
    const bf16* Bg = Wm + (size_t)(col0 + wave*32 + srow)*C_ + scol;
    bf16* Al = As + (wave*32)*32;        // wave-uniform
    bf16* Bl = Bs + (wave*32)*32;

    for (int k0 = 0; k0 < C_; k0 += 32) {
        __syncthreads();                 // prev iter's readers done
        #pragma unroll
        for (int i=0;i<2;i++){
            gl2lds(Ag + (size_t)i*16*C_ + k0, Al + i*16*32);
            gl2lds(Bg + (size_t)i*16*C_ + k0, Bl + i*16*32);
        }
        asm volatile("s_waitcnt vmcnt(0)" ::: "memory");
        __syncthreads();                 // staged data visible
        short8 af[4], bfv[4];
        #pragma unroll
        for (int mt=0; mt<4; ++mt) af[mt]  = *(const short8*)(As + (wm + mt*16 + l15)*32 + quad*8);
        #pragma unroll
        for (int nt=0; nt<4; ++nt) bfv[nt] = *(const short8*)(Bs + (wn + nt*16 + l15)*32 + quad*8);
        #pragma unroll
        for (int mt=0; mt<4; ++mt)
            #pragma unroll
            for (int nt=0; nt<4; ++nt)
                acc[mt][nt] = __builtin_amdgcn_mfma_f32_16x16x32_bf16(af[mt], bfv[nt], acc[mt][nt], 0,0,0);
    }
    #pragma unroll
    for (int mt=0; mt<4; ++mt)
        #pragma unroll
        for (int nt=0; nt<4; ++nt)
            #pragma unroll
            for (int r=0; r<4; ++r)
                stv(&Om[(size_t)(row0 + wm + mt*16 + quad*4 + r)*C_ + col0 + wn + nt*16 + l15], acc[mt][nt][r]);
}

// ---- RoPE + RMS-norm, in place on q or k ----
__global__ __launch_bounds__(256)
void rope_rms(bf16* __restrict__ q, bf16* __restrict__ k,
              const float* __restrict__ cosp, const float* __restrict__ sinp)
{
    const int wave = threadIdx.x >> 6, lane = threadIdx.x & 63;
    const long rb = (long)blockIdx.x*4 + wave;
    const int h = (int)(rb % H_);
    const long bt = rb / H_;
    const int t = (int)(bt % T_);
    bf16* buf = blockIdx.y ? k : q;
    const size_t base = (size_t)bt*C_ + (size_t)h*D_;
    float x1 = bf2f(buf[base + lane]);
    float x2 = bf2f(buf[base + 64 + lane]);
    float c  = cosp[(size_t)t*64 + lane];
    float s  = sinp[(size_t)t*64 + lane];
    float y1 =  x1*c + x2*s;
    float y2 = -x1*s + x2*c;
    float ss = y1*y1 + y2*y2;
    #pragma unroll
    for (int off=1; off<64; off<<=1) ss += __shfl_xor(ss, off);
    float sc = rsqrtf(ss*(1.0f/128.0f) + 1e-5f);
    buf[base + lane]      = f2bf(y1*sc);
    buf[base + 64 + lane] = f2bf(y2*sc);
}

// ---- V transpose: Vt[bh][d][t] ----
__global__ __launch_bounds__(256)
void vtrans(const bf16* __restrict__ V, bf16* __restrict__ Vt)
{
    __shared__ float st[64][65];
    const int tid = threadIdx.x;
    const int bh = blockIdx.z;
    const int b = bh / H_, h = bh % H_;
    const int t0 = blockIdx.x*64, d0 = blockIdx.y*64;
    #pragma unroll
    for (int i=0;i<16;i++){
        int e = tid + i*256;
        int r = e >> 6, dd = e & 63;
        st[r][dd] = bf2f(V[(size_t)(b*T_ + t0 + r)*C_ + h*D_ + d0 + dd]);
    }
    __syncthreads();
    #pragma unroll
    for (int i=0;i<16;i++){
        int e = tid + i*256;
        int dd = e >> 6, r = e & 63;
        Vt[((size_t)bh*D_ + d0 + dd)*T_ + t0 + r] = f2bf(st[r][dd]);
    }
}

// ---- Flash attention, causal. 4 independent waves/block; 16 q-rows/wave; 64-key chunks. ----
__global__ __launch_bounds__(256)
void attn(const bf16* __restrict__ Q, const bf16* __restrict__ K,
          const bf16* __restrict__ Vt, bf16* __restrict__ Y)
{
    __shared__ __align__(16) bf16 pt[4][16][72];   // per-wave P tile (144B rows, 16B aligned)
    const int wave = threadIdx.x >> 6;
    const int lane = threadIdx.x & 63;
    const int l15 = lane & 15, quad = lane >> 4;
    const int bh = blockIdx.y, b = bh / H_, h = bh % H_;
    const int bt0 = T_ - 64 - 64*blockIdx.x;       // reversed: big-work blocks first
    const int t0w = bt0 + wave*16;
    const size_t base = (size_t)b*T_*C_ + (size_t)h*D_;

    short8 qa[4];
    {
        const bf16* qp = Q + base + (size_t)(t0w + l15)*C_ + quad*8;
        #pragma unroll
        for (int kb=0; kb<4; ++kb) qa[kb] = *(const short8*)(qp + kb*32);
    }
    const f32x4 fzero = {0.f,0.f,0.f,0.f};
    f32x4 o[8];
    #pragma unroll
    for (int dt=0; dt<8; ++dt) o[dt] = fzero;
    float m[4] = {-1e30f,-1e30f,-1e30f,-1e30f};
    float l[4] = {0.f,0.f,0.f,0.f};
    const float scale = 0.08838834764831845f;      // 1/sqrt(128)
    const int nch = (t0w >> 6) + 1;                // 64-key chunks

    for (int ch=0; ch<nch; ++ch) {
        const int k0 = ch*64;
        const bool lastc = (ch == nch-1);
        f32x4 s[4];
        #pragma unroll
        for (int c=0;c<4;c++) s[c] = fzero;
        const bf16* kp = K + base + (size_t)(k0 + l15)*C_ + quad*8;
        #pragma unroll
        for (int c=0;c<4;c++){
            const bf16* kpc = kp + (size_t)(c*16)*C_;
            #pragma unroll
            for (int kb=0; kb<4; ++kb) {
                short8 bK = *(const short8*)(kpc + kb*32);
                s[c] = __builtin_amdgcn_mfma_f32_16x16x32_bf16(qa[kb], bK, s[c], 0,0,0);
            }
        }
        float alpha[4];
        #pragma unroll
        for (int r=0; r<4; ++r) {
            const int rt = t0w + quad*4 + r;
            float v[4];
            #pragma unroll
            for (int c=0;c<4;c++) v[c] = s[c][r]*scale;
            if (lastc) {
                #pragma unroll
                for (int c=0;c<4;c++) if (k0 + c*16 + l15 > rt) v[c] = -1e30f;
            }
            float mx = fmaxf(fmaxf(v[0],v[1]), fmaxf(v[2],v[3]));
            #pragma unroll
            for (int off=1; off<16; off<<=1) mx = fmaxf(mx, __shfl_xor(mx, off));
            const float mn = fmaxf(m[r], mx);
            alpha[r] = __expf(m[r] - mn);
            float p[4], rs = 0.f;
            #pragma unroll
            for (int c=0;c<4;c++){ p[c] = __expf(v[c] - mn); rs += p[c]; }
            #pragma unroll
            for (int off=1; off<16; off<<=1) rs += __shfl_xor(rs, off);
            l[r] = l[r]*alpha[r] + rs;
            m[r] = mn;
            #pragma unroll
            for (int c=0;c<4;c++) pt[wave][quad*4+r][c*16 + l15] = f2bf(p[c]);
        }
        #pragma unroll
        for (int dt=0; dt<8; ++dt)
            #pragma unroll
            for (int r=0; r<4; ++r) o[dt][r] *= alpha[r];
        asm volatile("s_waitcnt lgkmcnt(0)" ::: "memory");   // own wave's P writes done
        const short8 pa0 = *(const short8*)(&pt[wave][l15][quad*8]);
        const short8 pa1 = *(const short8*)(&pt[wave][l15][32 + quad*8]);
        const bf16* vp = Vt + ((size_t)bh*D_ + l15)*T_ + k0 + quad*8;
        #pragma unroll
        for (int dt=0; dt<8; ++dt) {
            short8 bV0 = *(const short8*)(vp + (size_t)dt*16*T_);
            short8 bV1 = *(const short8*)(vp + (size_t)dt*16*T_ + 32);
            o[dt] = __builtin_amdgcn_mfma_f32_16x16x32_bf16(pa0, bV0, o[dt], 0,0,0);
            o[dt] = __builtin_amdgcn_mfma_f32_16x16x32_bf16(pa1, bV1, o[dt], 0,0,0);
        }
    }
    #pragma unroll
    for (int r=0; r<4; ++r) l[r] = 1.0f / l[r];
    #pragma unroll
    for (int dt=0; dt<8; ++dt)
        #pragma unroll
        for (int r=0; r<4; ++r)
            Y[base + (size_t)(t0w + quad*4 + r)*C_ + dt*16 + l15] = f2bf(o[dt][r]*l[r]);
}

extern "C" void kernel_launch(void* const* d_in, const int* in_sizes, int n_in,
                              void* d_out, int out_size, void* d_ws, size_t ws_size,
                              hipStream_t stream)
{
    const float* x    = (const float*)d_in[0];
    const float* cosp = (const float*)d_in[1];
    const float* sinp = (const float*)d_in[2];
    const float* Wq   = (const float*)d_in[3];
    const float* Wk   = (const float*)d_in[4];
    const float* Wv   = (const float*)d_in[5];
    const float* Wp   = (const float*)d_in[6];
    float* out = (float*)d_out;

    const size_t NE = (size_t)BT_ * C_;
    const size_t NW = (size_t)C_ * C_;
    bf16* xb = (bf16*)d_ws;
    bf16* wb = xb + NE;
    bf16* q  = wb + 4*NW;
    bf16* k  = q + NE;
    bf16* v  = k + NE;
    bf16* y  = v + NE;
    bf16* vT = y + NE;

    cvt<<<dim3(NE/1024), 256, 0, stream>>>(x, xb);
    cvtW<<<dim3(NW/1024, 4), 256, 0, stream>>>(Wq, Wk, Wv, Wp, wb);
    gemm_nt<bf16><<<dim3(BT_/128, C_/128, 3), 256, 0, stream>>>(xb, wb, q, k, v);
    rope_rms<<<dim3(BT_*H_/4, 2), 256, 0, stream>>>(q, k, cosp, sinp);
    vtrans<<<dim3(T_/64, D_/64, B_*H_), 256, 0, stream>>>(v, vT);
    attn<<<dim3(T_/64, B_*H_), 256, 0, stream>>>(q, k, vT, y);
    gemm_nt<float><<<dim3(BT_/128, C_/128, 1), 256, 0, stream>>>(y, wb + 3*NW, out, out, out);
}

// Round 4
// 434.555 us; speedup vs baseline: 1.4387x; 1.3080x over previous
//
#include <hip/hip_runtime.h>
#include <hip/hip_bf16.h>

#define B_ 2
#define T_ 2048
#define C_ 1280
#define H_ 10
#define D_ 128
#define BT_ (B_*T_)

typedef __hip_bfloat16 bf16;
typedef __attribute__((ext_vector_type(8))) short short8;
typedef __attribute__((ext_vector_type(4))) float f32x4;

__device__ __forceinline__ float bf2f(bf16 v){ return __bfloat162float(v); }
__device__ __forceinline__ bf16  f2bf(float v){ return __float2bfloat16(v); }
__device__ __forceinline__ void stv(bf16* p, float v){ *p = f2bf(v); }
__device__ __forceinline__ void stv(float* p, float v){ *p = v; }

struct alignas(8) bf4 { bf16 a,b,c,d; };

__device__ __forceinline__ void gl2lds(const bf16* g, bf16* l) {
    __builtin_amdgcn_global_load_lds(
        (const __attribute__((address_space(1))) void*)g,
        (__attribute__((address_space(3))) void*)l,
        16, 0, 0);
}

// ---- fp32 -> bf16 bulk convert ----
__global__ __launch_bounds__(256)
void cvt(const float* __restrict__ s, bf16* __restrict__ d)
{
    const int i = (blockIdx.x*256 + threadIdx.x)*4;
    const float4 v = *(const float4*)(s + i);
    bf4 o = { f2bf(v.x), f2bf(v.y), f2bf(v.z), f2bf(v.w) };
    *(bf4*)(d + i) = o;
}

__global__ __launch_bounds__(256)
void cvtW(const float* __restrict__ s0, const float* __restrict__ s1,
          const float* __restrict__ s2, const float* __restrict__ s3,
          bf16* __restrict__ d)
{
    const int w = blockIdx.y;
    const float* s = (w==0)?s0:(w==1)?s1:(w==2)?s2:s3;
    const int i = (blockIdx.x*256 + threadIdx.x)*4;
    const float4 v = *(const float4*)(s + i);
    bf4 o = { f2bf(v.x), f2bf(v.y), f2bf(v.z), f2bf(v.w) };
    *(bf4*)(d + (size_t)w*C_*C_ + i) = o;
}

// ---- GEMM (m97 structure): O = A[4096,1280] @ W[1280,1280]^T, bf16 in, fp32 acc ----
template <typename OT>
__global__ __launch_bounds__(256)
void gemm_nt(const bf16* __restrict__ A, const bf16* __restrict__ Wb,
             OT* __restrict__ O0, OT* __restrict__ O1, OT* __restrict__ O2)
{
    __shared__ __align__(16) bf16 As[128*32];
    __shared__ __align__(16) bf16 Bs[128*32];
    const int z = blockIdx.z;
    const bf16* Wm = Wb + (size_t)z*C_*C_;
    OT*         Om = (z==0) ? O0 : (z==1) ? O1 : O2;
    const int wave = threadIdx.x >> 6;
    const int lane = threadIdx.x & 63;
    const int l15 = lane & 15, quad = lane >> 4;
    const int row0 = blockIdx.x*128;
    const int col0 = blockIdx.y*128;
    const int wm = (wave>>1)*64, wn = (wave&1)*64;
    const int srow = lane >> 2;
    const int scol = (lane & 3)*8;

    const f32x4 fzero = {0.f,0.f,0.f,0.f};
    f32x4 acc[4][4];
    #pragma unroll
    for (int i=0;i<4;i++)
        #pragma unroll
        for (int j=0;j<4;j++) acc[i][j] = fzero;

    const bf16* Ag = A  + (size_t)(row0 + wave*32 + srow)*C_ + scol;
    const bf16* Bg = Wm + (size_t)(col0 + wave*32 + srow)*C_ + scol;
    bf16* Al = As + (wave*32)*32;
    bf16* Bl = Bs + (wave*32)*32;

    for (int k0 = 0; k0 < C_; k0 += 32) {
        __syncthreads();
        #pragma unroll
        for (int i=0;i<2;i++){
            gl2lds(Ag + (size_t)i*16*C_ + k0, Al + i*16*32);
            gl2lds(Bg + (size_t)i*16*C_ + k0, Bl + i*16*32);
        }
        asm volatile("s_waitcnt vmcnt(0)" ::: "memory");
        __syncthreads();
        short8 af[4], bfv[4];
        #pragma unroll
        for (int mt=0; mt<4; ++mt) af[mt]  = *(const short8*)(As + (wm + mt*16 + l15)*32 + quad*8);
        #pragma unroll
        for (int nt=0; nt<4; ++nt) bfv[nt] = *(const short8*)(Bs + (wn + nt*16 + l15)*32 + quad*8);
        #pragma unroll
        for (int mt=0; mt<4; ++mt)
            #pragma unroll
            for (int nt=0; nt<4; ++nt)
                acc[mt][nt] = __builtin_amdgcn_mfma_f32_16x16x32_bf16(af[mt], bfv[nt], acc[mt][nt], 0,0,0);
    }
    #pragma unroll
    for (int mt=0; mt<4; ++mt)
        #pragma unroll
        for (int nt=0; nt<4; ++nt)
            #pragma unroll
            for (int r=0; r<4; ++r)
                stv(&Om[(size_t)(row0 + wm + mt*16 + quad*4 + r)*C_ + col0 + wn + nt*16 + l15], acc[mt][nt][r]);
}

// ---- RoPE + RMS-norm, in place ----
__global__ __launch_bounds__(256)
void rope_rms(bf16* __restrict__ q, bf16* __restrict__ k,
              const float* __restrict__ cosp, const float* __restrict__ sinp)
{
    const int wave = threadIdx.x >> 6, lane = threadIdx.x & 63;
    const long rb = (long)blockIdx.x*4 + wave;
    const int h = (int)(rb % H_);
    const long bt = rb / H_;
    const int t = (int)(bt % T_);
    bf16* buf = blockIdx.y ? k : q;
    const size_t base = (size_t)bt*C_ + (size_t)h*D_;
    float x1 = bf2f(buf[base + lane]);
    float x2 = bf2f(buf[base + 64 + lane]);
    float c  = cosp[(size_t)t*64 + lane];
    float s  = sinp[(size_t)t*64 + lane];
    float y1 =  x1*c + x2*s;
    float y2 = -x1*s + x2*c;
    float ss = y1*y1 + y2*y2;
    #pragma unroll
    for (int off=1; off<64; off<<=1) ss += __shfl_xor(ss, off);
    float sc = rsqrtf(ss*(1.0f/128.0f) + 1e-5f);
    buf[base + lane]      = f2bf(y1*sc);
    buf[base + 64 + lane] = f2bf(y2*sc);
}

// ---- V transpose: Vt[bh][d][t] ----
__global__ __launch_bounds__(256)
void vtrans(const bf16* __restrict__ V, bf16* __restrict__ Vt)
{
    __shared__ float st[64][65];
    const int tid = threadIdx.x;
    const int bh = blockIdx.z;
    const int b = bh / H_, h = bh % H_;
    const int t0 = blockIdx.x*64, d0 = blockIdx.y*64;
    #pragma unroll
    for (int i=0;i<16;i++){
        int e = tid + i*256;
        int r = e >> 6, dd = e & 63;
        st[r][dd] = bf2f(V[(size_t)(b*T_ + t0 + r)*C_ + h*D_ + d0 + dd]);
    }
    __syncthreads();
    #pragma unroll
    for (int i=0;i<16;i++){
        int e = tid + i*256;
        int dd = e >> 6, r = e & 63;
        Vt[((size_t)bh*D_ + d0 + dd)*T_ + t0 + r] = f2bf(st[r][dd]);
    }
}

// ---- Flash attention, causal, split-K (S=2), fixed softmax max. ----
// wave-task w in [0,5120): i=w>>1 selects (bh, qt) with qt pair-balanced; s=w&1 key-half.
// Scores bounded: q,k RMS-normed -> s <= sqrt(128)=M0. p=exp(s-M0); merge = plain sum.
#define M0_ 11.3137085f
__global__ __launch_bounds__(256)
void attn_sk(const bf16* __restrict__ Q, const bf16* __restrict__ K,
             const bf16* __restrict__ Vt,
             bf16* __restrict__ opart, float* __restrict__ lpart)
{
    __shared__ __align__(16) bf16 pt[4][16][72];
    const int wave = threadIdx.x >> 6, lane = threadIdx.x & 63;
    const int l15 = lane & 15, quad = lane >> 4;
    const int w = blockIdx.x*4 + wave;
    const int i = w >> 1, s = w & 1;
    const int bh = i >> 7, r128 = i & 127;
    const int qt = (r128 & 1) ? (127 - (r128 >> 1)) : (r128 >> 1);
    const int b = bh / H_, h = bh % H_;
    const int t0 = qt*16;
    const int nch = (qt >> 2) + 1;
    const int c0 = s ? (nch >> 1) : 0;
    const int c1 = s ? nch : (nch >> 1);
    const size_t base = (size_t)b*T_*C_ + (size_t)h*D_;
    const float scale = 0.08838834764831845f;   // 1/sqrt(128)

    short8 qa[4];
    {
        const bf16* qp = Q + base + (size_t)(t0 + l15)*C_ + quad*8;
        #pragma unroll
        for (int kb=0; kb<4; ++kb) qa[kb] = *(const short8*)(qp + kb*32);
    }
    const f32x4 fzero = {0.f,0.f,0.f,0.f};
    f32x4 o[8];
    #pragma unroll
    for (int dt=0; dt<8; ++dt) o[dt] = fzero;
    float lp[4] = {0.f,0.f,0.f,0.f};

    for (int ch=c0; ch<c1; ++ch) {
        const int k0 = ch*64;
        const bool lastc = (ch == nch-1);
        f32x4 sc4[4];
        #pragma unroll
        for (int c=0;c<4;c++) sc4[c] = fzero;
        const bf16* kp = K + base + (size_t)(k0 + l15)*C_ + quad*8;
        #pragma unroll
        for (int c=0;c<4;c++){
            const bf16* kpc = kp + (size_t)(c*16)*C_;
            #pragma unroll
            for (int kb=0; kb<4; ++kb) {
                short8 bK = *(const short8*)(kpc + kb*32);
                sc4[c] = __builtin_amdgcn_mfma_f32_16x16x32_bf16(qa[kb], bK, sc4[c], 0,0,0);
            }
        }
        #pragma unroll
        for (int r=0; r<4; ++r) {
            const int rt = t0 + quad*4 + r;
            float v[4];
            #pragma unroll
            for (int c=0;c<4;c++) v[c] = sc4[c][r]*scale;
            if (lastc) {
                #pragma unroll
                for (int c=0;c<4;c++) if (k0 + c*16 + l15 > rt) v[c] = -1e30f;
            }
            float p[4];
            #pragma unroll
            for (int c=0;c<4;c++) p[c] = __expf(v[c] - M0_);
            lp[r] += (p[0]+p[1]) + (p[2]+p[3]);
            #pragma unroll
            for (int c=0;c<4;c++) pt[wave][quad*4+r][c*16 + l15] = f2bf(p[c]);
        }
        asm volatile("s_waitcnt lgkmcnt(0)" ::: "memory");   // own wave's P writes visible
        const short8 pa0 = *(const short8*)(&pt[wave][l15][quad*8]);
        const short8 pa1 = *(const short8*)(&pt[wave][l15][32 + quad*8]);
        const bf16* vp = Vt + ((size_t)bh*D_ + l15)*T_ + k0 + quad*8;
        #pragma unroll
        for (int dt=0; dt<8; ++dt) {
            short8 bV0 = *(const short8*)(vp + (size_t)dt*16*T_);
            short8 bV1 = *(const short8*)(vp + (size_t)dt*16*T_ + 32);
            o[dt] = __builtin_amdgcn_mfma_f32_16x16x32_bf16(pa0, bV0, o[dt], 0,0,0);
            o[dt] = __builtin_amdgcn_mfma_f32_16x16x32_bf16(pa1, bV1, o[dt], 0,0,0);
        }
    }
    // deferred l reduction over the 16-lane group
    #pragma unroll
    for (int r=0; r<4; ++r) {
        #pragma unroll
        for (int off=1; off<16; off<<=1) lp[r] += __shfl_xor(lp[r], off);
    }
    bf16* ob = opart + (size_t)w*2048;
    #pragma unroll
    for (int dt=0; dt<8; ++dt)
        #pragma unroll
        for (int r=0; r<4; ++r)
            ob[(quad*4+r)*128 + dt*16 + l15] = f2bf(o[dt][r]);
    if (l15 == 0) {
        #pragma unroll
        for (int r=0; r<4; ++r) lpart[(size_t)w*16 + quad*4 + r] = lp[r];
    }
}

// ---- combine split-K partials -> y (bf16) ----
__global__ __launch_bounds__(256)
void combine(const bf16* __restrict__ opart, const float* __restrict__ lpart,
             bf16* __restrict__ Y)
{
    const int i = blockIdx.x;                 // 0..2559
    const int bh = i >> 7, r128 = i & 127;
    const int qt = (r128 & 1) ? (127 - (r128 >> 1)) : (r128 >> 1);
    const int b = bh / H_, h = bh % H_;
    const int t0 = qt*16;
    const int row = threadIdx.x >> 4;
    const int c8 = (threadIdx.x & 15)*8;
    const float li = 1.0f/(lpart[(size_t)(2*i)*16 + row] + lpart[(size_t)(2*i+1)*16 + row]);
    const bf16* pa = opart + (size_t)(2*i)*2048   + row*128 + c8;
    const bf16* pb = opart + (size_t)(2*i+1)*2048 + row*128 + c8;
    bf16* y = Y + (size_t)b*T_*C_ + (size_t)(t0+row)*C_ + (size_t)h*D_ + c8;
    #pragma unroll
    for (int j=0;j<8;j++) y[j] = f2bf((bf2f(pa[j]) + bf2f(pb[j]))*li);
}

extern "C" void kernel_launch(void* const* d_in, const int* in_sizes, int n_in,
                              void* d_out, int out_size, void* d_ws, size_t ws_size,
                              hipStream_t stream)
{
    const float* x    = (const float*)d_in[0];
    const float* cosp = (const float*)d_in[1];
    const float* sinp = (const float*)d_in[2];
    const float* Wq   = (const float*)d_in[3];
    const float* Wk   = (const float*)d_in[4];
    const float* Wv   = (const float*)d_in[5];
    const float* Wp   = (const float*)d_in[6];
    float* out = (float*)d_out;

    const size_t NE = (size_t)BT_ * C_;
    const size_t NW = (size_t)C_ * C_;
    bf16* xb = (bf16*)d_ws;
    bf16* wb = xb + NE;
    bf16* q  = wb + 4*NW;
    bf16* k  = q + NE;
    bf16* v  = k + NE;
    bf16* y  = v + NE;
    bf16* vT = y + NE;
    bf16* op = vT + NE;                   // split-K o partials: 5120 x 2048 bf16 (21 MB)
    float* lpart = (float*)(op + (size_t)5120*2048);  // 5120 x 16 f32

    cvt<<<dim3(NE/1024), 256, 0, stream>>>(x, xb);
    cvtW<<<dim3(NW/1024, 4), 256, 0, stream>>>(Wq, Wk, Wv, Wp, wb);
    gemm_nt<bf16><<<dim3(BT_/128, C_/128, 3), 256, 0, stream>>>(xb, wb, q, k, v);
    rope_rms<<<dim3(BT_*H_/4, 2), 256, 0, stream>>>(q, k, cosp, sinp);
    vtrans<<<dim3(T_/64, D_/64, B_*H_), 256, 0, stream>>>(v, vT);
    attn_sk<<<dim3(1280), 256, 0, stream>>>(q, k, vT, op, lpart);
    combine<<<dim3(2560), 256, 0, stream>>>(op, lpart, y);
    gemm_nt<float><<<dim3(BT_/128, C_/128, 1), 256, 0, stream>>>(y, wb + 3*NW, out, out, out);
}

// Round 5
// 359.472 us; speedup vs baseline: 1.7391x; 1.2089x over previous
//
#include <hip/hip_runtime.h>
#include <hip/hip_bf16.h>

#define B_ 2
#define T_ 2048
#define C_ 1280
#define H_ 10
#define D_ 128
#define BT_ (B_*T_)

typedef __hip_bfloat16 bf16;
typedef __attribute__((ext_vector_type(8))) short short8;
typedef __attribute__((ext_vector_type(4))) float f32x4;

__device__ __forceinline__ float bf2f(bf16 v){ return __bfloat162float(v); }
__device__ __forceinline__ bf16  f2bf(float v){ return __float2bfloat16(v); }
__device__ __forceinline__ void stv(bf16* p, float v){ *p = f2bf(v); }
__device__ __forceinline__ void stv(float* p, float v){ *p = v; }

struct alignas(8) bf4 { bf16 a,b,c,d; };

__device__ __forceinline__ void gl2lds(const bf16* g, bf16* l) {
    __builtin_amdgcn_global_load_lds(
        (const __attribute__((address_space(1))) void*)g,
        (__attribute__((address_space(3))) void*)l,
        16, 0, 0);
}

// ---- fp32 -> bf16 bulk convert ----
__global__ __launch_bounds__(256)
void cvt(const float* __restrict__ s, bf16* __restrict__ d)
{
    const int i = (blockIdx.x*256 + threadIdx.x)*4;
    const float4 v = *(const float4*)(s + i);
    bf4 o = { f2bf(v.x), f2bf(v.y), f2bf(v.z), f2bf(v.w) };
    *(bf4*)(d + i) = o;
}

__global__ __launch_bounds__(256)
void cvtW(const float* __restrict__ s0, const float* __restrict__ s1,
          const float* __restrict__ s2, const float* __restrict__ s3,
          bf16* __restrict__ d)
{
    const int w = blockIdx.y;
    const float* s = (w==0)?s0:(w==1)?s1:(w==2)?s2:s3;
    const int i = (blockIdx.x*256 + threadIdx.x)*4;
    const float4 v = *(const float4*)(s + i);
    bf4 o = { f2bf(v.x), f2bf(v.y), f2bf(v.z), f2bf(v.w) };
    *(bf4*)(d + (size_t)w*C_*C_ + i) = o;
}

// ---- GEMM: O = A[4096,1280] @ W[1280,1280]^T, bf16 in, fp32 acc, BK=64 ----
// 256 thr / 4 waves; block tile 128x128; staging = full 128B cachelines per row.
template <typename OT>
__global__ __launch_bounds__(256,3)
void gemm_nt(const bf16* __restrict__ A, const bf16* __restrict__ Wb,
             OT* __restrict__ O0, OT* __restrict__ O1, OT* __restrict__ O2)
{
    __shared__ __align__(16) bf16 As[128*64];   // 16 KB
    __shared__ __align__(16) bf16 Bs[128*64];   // 16 KB
    const int z = blockIdx.z;
    const bf16* Wm = Wb + (size_t)z*C_*C_;
    OT*         Om = (z==0) ? O0 : (z==1) ? O1 : O2;
    const int wave = threadIdx.x >> 6;
    const int lane = threadIdx.x & 63;
    const int l15 = lane & 15, quad = lane >> 4;
    const int row0 = blockIdx.x*128;
    const int col0 = blockIdx.y*128;
    const int wm = (wave>>1)*64, wn = (wave&1)*64;
    const int srow = lane >> 3;          // 0..7
    const int scol = (lane & 7)*8;       // 0..56

    const f32x4 fzero = {0.f,0.f,0.f,0.f};
    f32x4 acc[4][4];
    #pragma unroll
    for (int i=0;i<4;i++)
        #pragma unroll
        for (int j=0;j<4;j++) acc[i][j] = fzero;

    const bf16* Ag = A  + (size_t)(row0 + wave*32 + srow)*C_ + scol;
    const bf16* Bg = Wm + (size_t)(col0 + wave*32 + srow)*C_ + scol;
    bf16* Al = As + (wave*32)*64;
    bf16* Bl = Bs + (wave*32)*64;

    for (int k0 = 0; k0 < C_; k0 += 64) {
        __syncthreads();
        #pragma unroll
        for (int i=0;i<4;i++){
            gl2lds(Ag + (size_t)i*8*C_ + k0, Al + i*8*64);
            gl2lds(Bg + (size_t)i*8*C_ + k0, Bl + i*8*64);
        }
        asm volatile("s_waitcnt vmcnt(0)" ::: "memory");
        __syncthreads();
        #pragma unroll
        for (int h=0; h<2; ++h) {
            short8 af[4], bfv[4];
            #pragma unroll
            for (int mt=0; mt<4; ++mt) af[mt]  = *(const short8*)(As + (wm + mt*16 + l15)*64 + h*32 + quad*8);
            #pragma unroll
            for (int nt=0; nt<4; ++nt) bfv[nt] = *(const short8*)(Bs + (wn + nt*16 + l15)*64 + h*32 + quad*8);
            #pragma unroll
            for (int mt=0; mt<4; ++mt)
                #pragma unroll
                for (int nt=0; nt<4; ++nt)
                    acc[mt][nt] = __builtin_amdgcn_mfma_f32_16x16x32_bf16(af[mt], bfv[nt], acc[mt][nt], 0,0,0);
        }
    }
    #pragma unroll
    for (int mt=0; mt<4; ++mt)
        #pragma unroll
        for (int nt=0; nt<4; ++nt)
            #pragma unroll
            for (int r=0; r<4; ++r)
                stv(&Om[(size_t)(row0 + wm + mt*16 + quad*4 + r)*C_ + col0 + wn + nt*16 + l15], acc[mt][nt][r]);
}

// ---- RoPE + RMS-norm, in place ----
__global__ __launch_bounds__(256)
void rope_rms(bf16* __restrict__ q, bf16* __restrict__ k,
              const float* __restrict__ cosp, const float* __restrict__ sinp)
{
    const int wave = threadIdx.x >> 6, lane = threadIdx.x & 63;
    const long rb = (long)blockIdx.x*4 + wave;
    const int h = (int)(rb % H_);
    const long bt = rb / H_;
    const int t = (int)(bt % T_);
    bf16* buf = blockIdx.y ? k : q;
    const size_t base = (size_t)bt*C_ + (size_t)h*D_;
    float x1 = bf2f(buf[base + lane]);
    float x2 = bf2f(buf[base + 64 + lane]);
    float c  = cosp[(size_t)t*64 + lane];
    float s  = sinp[(size_t)t*64 + lane];
    float y1 =  x1*c + x2*s;
    float y2 = -x1*s + x2*c;
    float ss = y1*y1 + y2*y2;
    #pragma unroll
    for (int off=1; off<64; off<<=1) ss += __shfl_xor(ss, off);
    float sc = rsqrtf(ss*(1.0f/128.0f) + 1e-5f);
    buf[base + lane]      = f2bf(y1*sc);
    buf[base + 64 + lane] = f2bf(y2*sc);
}

// ---- V transpose: Vt[bh][d][t] ----
__global__ __launch_bounds__(256)
void vtrans(const bf16* __restrict__ V, bf16* __restrict__ Vt)
{
    __shared__ float st[64][65];
    const int tid = threadIdx.x;
    const int bh = blockIdx.z;
    const int b = bh / H_, h = bh % H_;
    const int t0 = blockIdx.x*64, d0 = blockIdx.y*64;
    #pragma unroll
    for (int i=0;i<16;i++){
        int e = tid + i*256;
        int r = e >> 6, dd = e & 63;
        st[r][dd] = bf2f(V[(size_t)(b*T_ + t0 + r)*C_ + h*D_ + d0 + dd]);
    }
    __syncthreads();
    #pragma unroll
    for (int i=0;i<16;i++){
        int e = tid + i*256;
        int dd = e >> 6, r = e & 63;
        Vt[((size_t)bh*D_ + d0 + dd)*T_ + t0 + r] = f2bf(st[r][dd]);
    }
}

// ---- Flash attention v3: block = 32-row q-tile; 4 waves = 4 key-range quarters;
// fixed softmax max M0 (q,k RMS-normed -> score <= sqrt(128)); in-LDS split combine. ----
#define M0_ 11.3137085f
__global__ __launch_bounds__(256,3)
void attn(const bf16* __restrict__ Q, const bf16* __restrict__ K,
          const bf16* __restrict__ Vt, bf16* __restrict__ Y)
{
    // per-wave union region: P-tile (32 x 72 bf16) during loop, o-partial (32 x 136 bf16) after
    __shared__ __align__(16) bf16 smem[4][4352];
    __shared__ float lsh[4][32];
    const int wave = threadIdx.x >> 6, lane = threadIdx.x & 63;
    const int l15 = lane & 15, quad = lane >> 4;
    const int bh = blockIdx.x >> 6;
    const int j  = blockIdx.x & 63;
    const int qt = (j & 1) ? (63 - (j >> 1)) : (j >> 1);   // interleave for CU balance
    const int b = bh / H_, h = bh % H_;
    const int t0 = qt*32;
    const int nch = (qt >> 1) + 1;                         // 64-key chunks in causal range
    const int c0 = (wave*nch) >> 2;
    const int c1 = ((wave+1)*nch) >> 2;
    const size_t base = (size_t)b*T_*C_ + (size_t)h*D_;
    const float scale = 0.08838834764831845f;              // 1/sqrt(128)
    bf16* pt = smem[wave];

    short8 qa[2][4];
    #pragma unroll
    for (int tl=0; tl<2; ++tl) {
        const bf16* qp = Q + base + (size_t)(t0 + tl*16 + l15)*C_ + quad*8;
        #pragma unroll
        for (int kb=0; kb<4; ++kb) qa[tl][kb] = *(const short8*)(qp + kb*32);
    }
    const f32x4 fzero = {0.f,0.f,0.f,0.f};
    f32x4 o[2][8];
    #pragma unroll
    for (int tl=0; tl<2; ++tl)
        #pragma unroll
        for (int dt=0; dt<8; ++dt) o[tl][dt] = fzero;
    float lp[2][4] = {{0,0,0,0},{0,0,0,0}};

    for (int ch=c0; ch<c1; ++ch) {
        const int k0 = ch*64;
        const bool lastc = (ch == nch-1);
        f32x4 sc4[2][4];
        #pragma unroll
        for (int tl=0; tl<2; ++tl)
            #pragma unroll
            for (int c=0;c<4;c++) sc4[tl][c] = fzero;
        const bf16* kp = K + base + (size_t)(k0 + l15)*C_ + quad*8;
        #pragma unroll
        for (int c=0;c<4;c++){
            const bf16* kpc = kp + (size_t)(c*16)*C_;
            #pragma unroll
            for (int kb=0; kb<4; ++kb) {
                short8 bK = *(const short8*)(kpc + kb*32);
                sc4[0][c] = __builtin_amdgcn_mfma_f32_16x16x32_bf16(qa[0][kb], bK, sc4[0][c], 0,0,0);
                sc4[1][c] = __builtin_amdgcn_mfma_f32_16x16x32_bf16(qa[1][kb], bK, sc4[1][c], 0,0,0);
            }
        }
        #pragma unroll
        for (int tl=0; tl<2; ++tl)
            #pragma unroll
            for (int r=0; r<4; ++r) {
                const int rt = t0 + tl*16 + quad*4 + r;
                float v[4];
                #pragma unroll
                for (int c=0;c<4;c++) v[c] = sc4[tl][c][r]*scale;
                if (lastc) {
                    #pragma unroll
                    for (int c=0;c<4;c++) if (k0 + c*16 + l15 > rt) v[c] = -1e30f;
                }
                float p[4];
                #pragma unroll
                for (int c=0;c<4;c++) p[c] = __expf(v[c] - M0_);
                lp[tl][r] += (p[0]+p[1]) + (p[2]+p[3]);
                #pragma unroll
                for (int c=0;c<4;c++) pt[(tl*16+quad*4+r)*72 + c*16 + l15] = f2bf(p[c]);
            }
        asm volatile("s_waitcnt lgkmcnt(0)" ::: "memory");   // own wave's P writes visible
        short8 pa[2][2];
        #pragma unroll
        for (int tl=0; tl<2; ++tl)
            #pragma unroll
            for (int ks=0; ks<2; ++ks)
                pa[tl][ks] = *(const short8*)(pt + (tl*16+l15)*72 + ks*32 + quad*8);
        const bf16* vp = Vt + ((size_t)bh*D_ + l15)*T_ + k0 + quad*8;
        #pragma unroll
        for (int dt=0; dt<8; ++dt) {
            #pragma unroll
            for (int ks=0; ks<2; ++ks) {
                short8 bV = *(const short8*)(vp + (size_t)dt*16*T_ + ks*32);
                o[0][dt] = __builtin_amdgcn_mfma_f32_16x16x32_bf16(pa[0][ks], bV, o[0][dt], 0,0,0);
                o[1][dt] = __builtin_amdgcn_mfma_f32_16x16x32_bf16(pa[1][ks], bV, o[1][dt], 0,0,0);
            }
        }
    }
    // reduce l over the 16-lane group; write wave partials to LDS
    #pragma unroll
    for (int tl=0; tl<2; ++tl)
        #pragma unroll
        for (int r=0; r<4; ++r) {
            #pragma unroll
            for (int off=1; off<16; off<<=1) lp[tl][r] += __shfl_xor(lp[tl][r], off);
        }
    if (l15 == 0) {
        #pragma unroll
        for (int tl=0; tl<2; ++tl)
            #pragma unroll
            for (int r=0; r<4; ++r) lsh[wave][tl*16 + quad*4 + r] = lp[tl][r];
    }
    #pragma unroll
    for (int tl=0; tl<2; ++tl)
        #pragma unroll
        for (int dt=0; dt<8; ++dt)
            #pragma unroll
            for (int r=0; r<4; ++r)
                pt[(tl*16+quad*4+r)*136 + dt*16 + l15] = f2bf(o[tl][dt][r]);
    __syncthreads();
    // combine 4 wave-partials: 256 thr = 32 rows x 8 d-groups of 16
    {
        const int row = threadIdx.x >> 3;
        const int d0 = (threadIdx.x & 7)*16;
        const float li = 1.0f/(lsh[0][row]+lsh[1][row]+lsh[2][row]+lsh[3][row]);
        float s16[16];
        #pragma unroll
        for (int e=0;e<16;e++) s16[e] = 0.f;
        #pragma unroll
        for (int wv=0; wv<4; ++wv) {
            const bf16* pp = smem[wv] + row*136 + d0;
            #pragma unroll
            for (int e=0;e<16;e++) s16[e] += bf2f(pp[e]);
        }
        bf16 ov[16];
        #pragma unroll
        for (int e=0;e<16;e++) ov[e] = f2bf(s16[e]*li);
        bf16* yp = Y + base + (size_t)(t0 + row)*C_ + d0;
        *(short8*)(yp)   = *(short8*)(&ov[0]);
        *(short8*)(yp+8) = *(short8*)(&ov[8]);
    }
}

extern "C" void kernel_launch(void* const* d_in, const int* in_sizes, int n_in,
                              void* d_out, int out_size, void* d_ws, size_t ws_size,
                              hipStream_t stream)
{
    const float* x    = (const float*)d_in[0];
    const float* cosp = (const float*)d_in[1];
    const float* sinp = (const float*)d_in[2];
    const float* Wq   = (const float*)d_in[3];
    const float* Wk   = (const float*)d_in[4];
    const float* Wv   = (const float*)d_in[5];
    const float* Wp   = (const float*)d_in[6];
    float* out = (float*)d_out;

    const size_t NE = (size_t)BT_ * C_;
    const size_t NW = (size_t)C_ * C_;
    bf16* xb = (bf16*)d_ws;
    bf16* wb = xb + NE;
    bf16* q  = wb + 4*NW;
    bf16* k  = q + NE;
    bf16* v  = k + NE;
    bf16* y  = v + NE;
    bf16* vT = y + NE;

    cvt<<<dim3(NE/1024), 256, 0, stream>>>(x, xb);
    cvtW<<<dim3(NW/1024, 4), 256, 0, stream>>>(Wq, Wk, Wv, Wp, wb);
    gemm_nt<bf16><<<dim3(BT_/128, C_/128, 3), 256, 0, stream>>>(xb, wb, q, k, v);
    rope_rms<<<dim3(BT_*H_/4, 2), 256, 0, stream>>>(q, k, cosp, sinp);
    vtrans<<<dim3(T_/64, D_/64, B_*H_), 256, 0, stream>>>(v, vT);
    attn<<<dim3(B_*H_*64), 256, 0, stream>>>(q, k, vT, y);
    gemm_nt<float><<<dim3(BT_/128, C_/128, 1), 256, 0, stream>>>(y, wb + 3*NW, out, out, out);
}